// Round 1
// baseline (12058.492 us; speedup 1.0000x reference)
//
#include <hip/hip_runtime.h>
#include <hip/hip_bf16.h>
#include <math.h>

#define B_ 64
#define S_ 512
#define I_ 512
#define H_ 1024

typedef __attribute__((ext_vector_type(8))) short short8;
typedef __attribute__((ext_vector_type(4))) short short4v;
typedef __attribute__((ext_vector_type(4))) float f32x4;

__device__ inline short bf16bits(float f) {
    __hip_bfloat16 h = __float2bfloat16(f);
    return __builtin_bit_cast(short, h);
}

// ---------------- Phase A: x_proj = X @ W_ih^T + (b_ih + b_hh) -> d_out ----------------
// C[M=32768, N=1024], K=512. NT GEMM (both A and B are K-contiguous row-major).
// 128x128 block tile, BK=32, 256 threads = 4 waves in 2x2 of 64x64, 16x16x32 bf16 MFMA.
#define BM 128
#define BN 128
#define BK 32
#define LDT 40   // padded LDS row length in bf16 elems (32 + 8)

__global__ __launch_bounds__(256) void xproj_gemm(const float* __restrict__ X,
                                                  const float* __restrict__ Wih,
                                                  const float* __restrict__ bih,
                                                  const float* __restrict__ bhh,
                                                  float* __restrict__ out) {
    __shared__ __hip_bfloat16 sA[BM * LDT];
    __shared__ __hip_bfloat16 sB[BN * LDT];
    const int tid  = threadIdx.x;
    const int m0   = blockIdx.x * BM;   // 256 m-tiles
    const int n0   = blockIdx.y * BN;   // 8 n-tiles
    const int wave = tid >> 6;
    const int lane = tid & 63;
    const int quad = lane >> 4;
    const int l16  = lane & 15;
    const int wm   = (wave >> 1) * 64;
    const int wn   = (wave & 1) * 64;

    f32x4 acc[4][4] = {};

    for (int k0 = 0; k0 < I_; k0 += BK) {
        // stage A(128x32) and B(128x32) fp32 -> bf16 LDS
#pragma unroll
        for (int i = 0; i < 4; ++i) {
            int idx = tid + i * 256;          // 0..1023
            int r   = idx >> 3;               // 0..127
            int c4  = idx & 7;                // 0..7 (float4 column group)
            f32x4 a = *reinterpret_cast<const f32x4*>(X   + (size_t)(m0 + r) * I_ + k0 + c4 * 4);
            f32x4 b = *reinterpret_cast<const f32x4*>(Wih + (size_t)(n0 + r) * I_ + k0 + c4 * 4);
            short4v ap, bp;
            ap[0] = bf16bits(a[0]); ap[1] = bf16bits(a[1]); ap[2] = bf16bits(a[2]); ap[3] = bf16bits(a[3]);
            bp[0] = bf16bits(b[0]); bp[1] = bf16bits(b[1]); bp[2] = bf16bits(b[2]); bp[3] = bf16bits(b[3]);
            int off = r * LDT + c4 * 4;
            *reinterpret_cast<short4v*>(&sA[off]) = ap;
            *reinterpret_cast<short4v*>(&sB[off]) = bp;
        }
        __syncthreads();

        short8 af[4], bf[4];
#pragma unroll
        for (int mt = 0; mt < 4; ++mt)
            af[mt] = *reinterpret_cast<const short8*>(&sA[(wm + mt * 16 + l16) * LDT + quad * 8]);
#pragma unroll
        for (int nt = 0; nt < 4; ++nt)
            bf[nt] = *reinterpret_cast<const short8*>(&sB[(wn + nt * 16 + l16) * LDT + quad * 8]);
#pragma unroll
        for (int mt = 0; mt < 4; ++mt)
#pragma unroll
            for (int nt = 0; nt < 4; ++nt)
                acc[mt][nt] = __builtin_amdgcn_mfma_f32_16x16x32_bf16(af[mt], bf[nt], acc[mt][nt], 0, 0, 0);
        __syncthreads();
    }

    // epilogue: C/D layout row=(lane>>4)*4+reg, col=lane&15
#pragma unroll
    for (int mt = 0; mt < 4; ++mt) {
#pragma unroll
        for (int nt = 0; nt < 4; ++nt) {
            int gm = m0 + wm + mt * 16 + quad * 4;
            int gn = n0 + wn + nt * 16 + l16;
            float bias = bih[gn] + bhh[gn];
#pragma unroll
            for (int r = 0; r < 4; ++r)
                out[(size_t)(gm + r) * H_ + gn] = acc[mt][nt][r] + bias;
        }
    }
}

// ---------------- Phase B: persistent recurrent kernel ----------------
// 256 blocks = 4 batch-groups (16 batches) x 64 j-blocks (16 columns).
// W_hh slice (16x1024) bf16 stationary in LDS; h double-buffered bf16 in ws.
// Per step: K split 4x256 across waves, 8 MFMAs/wave, LDS cross-wave reduce,
// tanh + write d_out(fp32) + h(bf16), then group barrier (monotonic counter).
#define WLD 1032   // padded LDS row length for W (1024 + 8)

__global__ __launch_bounds__(256) void rnn_steps(const float* __restrict__ Whh,
                                                 float* __restrict__ out,
                                                 __hip_bfloat16* __restrict__ hbuf,
                                                 unsigned int* __restrict__ cnt) {
    __shared__ __hip_bfloat16 Wl[16 * WLD];
    __shared__ float red[4][16][17];
    const int tid  = threadIdx.x;
    const int bid  = blockIdx.x;
    const int g    = bid >> 6;        // batch group 0..3
    const int jblk = bid & 63;        // j block 0..63
    const int j0   = jblk * 16;
    const int b0   = g * 16;
    const int wave = tid >> 6;
    const int lane = tid & 63;
    const int quad = lane >> 4;
    const int l16  = lane & 15;
    const int m    = tid >> 4;        // epilogue row (batch within tile)
    const int n    = tid & 15;        // epilogue col (j within tile)

    // stage W_hh rows j0..j0+15 fp32 -> bf16 LDS
    for (int idx = tid; idx < 16 * 256; idx += 256) {
        int r  = idx >> 8;            // 0..15
        int c4 = idx & 255;           // float4 group 0..255
        f32x4 w = *reinterpret_cast<const f32x4*>(Whh + (size_t)(j0 + r) * H_ + c4 * 4);
        short4v wp;
        wp[0] = bf16bits(w[0]); wp[1] = bf16bits(w[1]); wp[2] = bf16bits(w[2]); wp[3] = bf16bits(w[3]);
        *reinterpret_cast<short4v*>(&Wl[r * WLD + c4 * 4]) = wp;
    }
    __syncthreads();

    const size_t orow = (size_t)(b0 + m) * S_ * H_ + (j0 + n);   // + t*H_ per step
    unsigned int* mycnt = cnt + g * 16;                          // 64B-spaced counters

    for (int t = 0; t < S_; ++t) {
        float val;
        if (t == 0) {
            val = tanhf(out[orow]);
        } else {
            // wait for all 64 blocks of this group to finish step t-1
            if (tid == 0) {
                unsigned int target = (unsigned int)t * 64u;
                int guard = 0;
                while (__hip_atomic_load(mycnt, __ATOMIC_ACQUIRE, __HIP_MEMORY_SCOPE_AGENT) < target) {
                    if (++guard > 4000000) break;   // anti-hang safety; correctness checked by harness
                }
            }
            __syncthreads();

            const __hip_bfloat16* hprev = hbuf + (size_t)((t - 1) & 1) * (B_ * H_);
            f32x4 acc = {0.f, 0.f, 0.f, 0.f};
            const int kbase = wave * 256;
#pragma unroll
            for (int i = 0; i < 8; ++i) {
                int k = kbase + i * 32 + quad * 8;
                short8 av = *reinterpret_cast<const short8*>(hprev + (size_t)(b0 + l16) * H_ + k);
                short8 bv = *reinterpret_cast<const short8*>(&Wl[l16 * WLD + k]);
                acc = __builtin_amdgcn_mfma_f32_16x16x32_bf16(av, bv, acc, 0, 0, 0);
            }
#pragma unroll
            for (int r = 0; r < 4; ++r)
                red[wave][quad * 4 + r][l16] = acc[r];
            __syncthreads();

            float s = red[0][m][n] + red[1][m][n] + red[2][m][n] + red[3][m][n];
            val = tanhf(out[orow + (size_t)t * H_] + s);
        }

        out[orow + (size_t)t * H_] = val;
        hbuf[(size_t)(t & 1) * (B_ * H_) + (size_t)(b0 + m) * H_ + (j0 + n)] = __float2bfloat16(val);
        __syncthreads();   // all stores issued + red free for next step

        if (t < S_ - 1) {
            if (tid == 0) {
                __threadfence();   // device-scope release of this block's h writes
                __hip_atomic_fetch_add(mycnt, 1u, __ATOMIC_RELEASE, __HIP_MEMORY_SCOPE_AGENT);
            }
        }
    }
}

extern "C" void kernel_launch(void* const* d_in, const int* in_sizes, int n_in,
                              void* d_out, int out_size, void* d_ws, size_t ws_size,
                              hipStream_t stream) {
    const float* x   = (const float*)d_in[0];   // (B,S,I)
    const float* Wih = (const float*)d_in[1];   // (H,I)
    const float* Whh = (const float*)d_in[2];   // (H,H)
    const float* bih = (const float*)d_in[3];   // (H)
    const float* bhh = (const float*)d_in[4];   // (H)
    float* out = (float*)d_out;                 // (B,S,H)

    unsigned int* cnt = (unsigned int*)d_ws;                      // 256 B of counters
    __hip_bfloat16* hbuf = (__hip_bfloat16*)((char*)d_ws + 256);  // 2 x 64 x 1024 bf16

    hipMemsetAsync(d_ws, 0, 256, stream);       // zero barrier counters every call

    dim3 gA(256, 8);
    xproj_gemm<<<gA, 256, 0, stream>>>(x, Wih, bih, bhh, out);
    rnn_steps<<<256, 256, 0, stream>>>(Whh, out, hbuf, cnt);
}

// Round 2
// 2315.944 us; speedup vs baseline: 5.2067x; 5.2067x over previous
//
#include <hip/hip_runtime.h>
#include <hip/hip_bf16.h>
#include <math.h>

#define B_ 64
#define S_ 512
#define I_ 512
#define H_ 1024

typedef __attribute__((ext_vector_type(8))) short short8;
typedef __attribute__((ext_vector_type(4))) short short4v;
typedef __attribute__((ext_vector_type(4))) float f32x4;

__device__ inline short bf16bits(float f) {
    __hip_bfloat16 h = __float2bfloat16(f);
    return __builtin_bit_cast(short, h);
}

// ---------------- Phase A: x_proj = X @ W_ih^T + (b_ih + b_hh) -> d_out ----------------
// C[M=32768, N=1024], K=512. NT GEMM. 128x128 tile, BK=32, 4 waves 2x2, 16x16x32 bf16 MFMA.
#define BM 128
#define BN 128
#define BK 32
#define LDT 40   // padded LDS row (32 + 8 bf16)

__global__ __launch_bounds__(256) void xproj_gemm(const float* __restrict__ X,
                                                  const float* __restrict__ Wih,
                                                  const float* __restrict__ bih,
                                                  const float* __restrict__ bhh,
                                                  float* __restrict__ out) {
    __shared__ __hip_bfloat16 sA[BM * LDT];
    __shared__ __hip_bfloat16 sB[BN * LDT];
    const int tid  = threadIdx.x;
    const int m0   = blockIdx.x * BM;
    const int n0   = blockIdx.y * BN;
    const int wave = tid >> 6;
    const int lane = tid & 63;
    const int quad = lane >> 4;
    const int l16  = lane & 15;
    const int wm   = (wave >> 1) * 64;
    const int wn   = (wave & 1) * 64;

    f32x4 acc[4][4] = {};

    for (int k0 = 0; k0 < I_; k0 += BK) {
#pragma unroll
        for (int i = 0; i < 4; ++i) {
            int idx = tid + i * 256;
            int r   = idx >> 3;
            int c4  = idx & 7;
            f32x4 a = *reinterpret_cast<const f32x4*>(X   + (size_t)(m0 + r) * I_ + k0 + c4 * 4);
            f32x4 b = *reinterpret_cast<const f32x4*>(Wih + (size_t)(n0 + r) * I_ + k0 + c4 * 4);
            short4v ap, bp;
            ap[0] = bf16bits(a[0]); ap[1] = bf16bits(a[1]); ap[2] = bf16bits(a[2]); ap[3] = bf16bits(a[3]);
            bp[0] = bf16bits(b[0]); bp[1] = bf16bits(b[1]); bp[2] = bf16bits(b[2]); bp[3] = bf16bits(b[3]);
            int off = r * LDT + c4 * 4;
            *reinterpret_cast<short4v*>(&sA[off]) = ap;
            *reinterpret_cast<short4v*>(&sB[off]) = bp;
        }
        __syncthreads();

        short8 af[4], bf[4];
#pragma unroll
        for (int mt = 0; mt < 4; ++mt)
            af[mt] = *reinterpret_cast<const short8*>(&sA[(wm + mt * 16 + l16) * LDT + quad * 8]);
#pragma unroll
        for (int nt = 0; nt < 4; ++nt)
            bf[nt] = *reinterpret_cast<const short8*>(&sB[(wn + nt * 16 + l16) * LDT + quad * 8]);
#pragma unroll
        for (int mt = 0; mt < 4; ++mt)
#pragma unroll
            for (int nt = 0; nt < 4; ++nt)
                acc[mt][nt] = __builtin_amdgcn_mfma_f32_16x16x32_bf16(af[mt], bf[nt], acc[mt][nt], 0, 0, 0);
        __syncthreads();
    }

#pragma unroll
    for (int mt = 0; mt < 4; ++mt) {
#pragma unroll
        for (int nt = 0; nt < 4; ++nt) {
            int gm = m0 + wm + mt * 16 + quad * 4;
            int gn = n0 + wn + nt * 16 + l16;
            float bias = bih[gn] + bhh[gn];
#pragma unroll
            for (int r = 0; r < 4; ++r)
                out[(size_t)(gm + r) * H_ + gn] = acc[mt][nt][r] + bias;
        }
    }
}

// ---------------- Phase B: persistent recurrent kernel ----------------
// 256 blocks = 4 groups (16 batches) x 64 j-blocks (16 cols).
// Sync protocol (the round-1 fix): NO release fences / NO threadfence in the loop.
//  - h stores: 4B agent-scope RELAXED atomic stores (sc1 -> write to Infinity Cache,
//    never dirty in L2, so no buffer_wbl2 is ever needed).
//  - __syncthreads() drains each wave's vmcnt (compiler emits s_waitcnt vmcnt(0)
//    before s_barrier), so after the barrier ALL h stores are at the MALL.
//  - counter bump: RELAXED agent atomic add (coherence point = MALL = where h lives).
//  - waiters: RELAXED spin + one ACQUIRE load (single buffer_inv) after target reached.
//  - out[] stores nontemporal: keeps L2 clean, data flushed at kernel end.
#define WLD 1032   // padded LDS row for W (1024 + 8)

__global__ __launch_bounds__(256) void rnn_steps(const float* __restrict__ Whh,
                                                 float* __restrict__ out,
                                                 unsigned short* __restrict__ hbuf,
                                                 unsigned int* __restrict__ cnt) {
    __shared__ __hip_bfloat16 Wl[16 * WLD];
    __shared__ float red[4][16][17];
    const int tid  = threadIdx.x;
    const int bid  = blockIdx.x;
    const int g    = bid >> 6;        // batch group 0..3
    const int jblk = bid & 63;        // j block 0..63
    const int j0   = jblk * 16;
    const int b0   = g * 16;
    const int wave = tid >> 6;
    const int lane = tid & 63;
    const int quad = lane >> 4;
    const int l16  = lane & 15;
    const int m    = tid >> 4;        // batch within tile
    const int n    = tid & 15;        // j within tile

    // stage W_hh rows j0..j0+15 fp32 -> bf16 LDS
    for (int idx = tid; idx < 16 * 256; idx += 256) {
        int r  = idx >> 8;
        int c4 = idx & 255;
        f32x4 w = *reinterpret_cast<const f32x4*>(Whh + (size_t)(j0 + r) * H_ + c4 * 4);
        short4v wp;
        wp[0] = bf16bits(w[0]); wp[1] = bf16bits(w[1]); wp[2] = bf16bits(w[2]); wp[3] = bf16bits(w[3]);
        *reinterpret_cast<short4v*>(&Wl[r * WLD + c4 * 4]) = wp;
    }
    __syncthreads();

    const size_t orow = (size_t)(b0 + m) * S_ * H_ + (j0 + n);
    unsigned int* mycnt = cnt + g * 32;   // 128-B spaced counters

    for (int t = 0; t < S_; ++t) {
        // prefetch x_proj for this step (independent of h) -- hides HBM latency
        // behind the barrier wait.
        float xp = __builtin_nontemporal_load(out + orow + (size_t)t * H_);
        float s = 0.f;

        if (t > 0) {
            if (tid == 0) {
                const unsigned int target = (unsigned int)t * 64u;
                int guard = 0;
                while (__hip_atomic_load(mycnt, __ATOMIC_RELAXED, __HIP_MEMORY_SCOPE_AGENT) < target) {
                    __builtin_amdgcn_s_sleep(1);
                    if (++guard > 1000000) break;   // anti-hang; harness re-validates
                }
                // single acquire (one buffer_inv) now that target is reached
                (void)__hip_atomic_load(mycnt, __ATOMIC_ACQUIRE, __HIP_MEMORY_SCOPE_AGENT);
            }
            __syncthreads();   // #1: all waves see fresh memory

            const unsigned short* hprev = hbuf + (size_t)((t - 1) & 1) * (B_ * H_);
            f32x4 acc = {0.f, 0.f, 0.f, 0.f};
            const int kbase = wave * 256;
#pragma unroll
            for (int i = 0; i < 8; ++i) {
                int k = kbase + i * 32 + quad * 8;
                short8 av = *reinterpret_cast<const short8*>(hprev + (size_t)(b0 + l16) * H_ + k);
                short8 bv = *reinterpret_cast<const short8*>(&Wl[l16 * WLD + k]);
                acc = __builtin_amdgcn_mfma_f32_16x16x32_bf16(av, bv, acc, 0, 0, 0);
            }
#pragma unroll
            for (int r = 0; r < 4; ++r)
                red[wave][quad * 4 + r][l16] = acc[r];
            __syncthreads();   // #2: reduction staged

            s = red[0][m][n] + red[1][m][n] + red[2][m][n] + red[3][m][n];
        }

        float val = tanhf(xp + s);
        __builtin_nontemporal_store(val, out + orow + (size_t)t * H_);

        // pack (n, n+1) bf16 pair in-register via lane shuffle; even-n lanes store 4B
        float nb = __shfl_xor(val, 1, 64);
        unsigned int pair = ((unsigned int)(unsigned short)bf16bits(nb) << 16)
                          | (unsigned int)(unsigned short)bf16bits(val);
        if ((n & 1) == 0) {
            unsigned int* dst = (unsigned int*)(hbuf + (size_t)(t & 1) * (B_ * H_)
                                                + (size_t)(b0 + m) * H_ + (j0 + n));
            __hip_atomic_store(dst, pair, __ATOMIC_RELAXED, __HIP_MEMORY_SCOPE_AGENT);
        }
        __syncthreads();   // #3: drains every wave's sc1 h-stores (vmcnt(0) before s_barrier)

        if (t < S_ - 1 && tid == 0) {
            __hip_atomic_fetch_add(mycnt, 1u, __ATOMIC_RELAXED, __HIP_MEMORY_SCOPE_AGENT);
        }
    }
}

extern "C" void kernel_launch(void* const* d_in, const int* in_sizes, int n_in,
                              void* d_out, int out_size, void* d_ws, size_t ws_size,
                              hipStream_t stream) {
    const float* x   = (const float*)d_in[0];   // (B,S,I)
    const float* Wih = (const float*)d_in[1];   // (H,I)
    const float* Whh = (const float*)d_in[2];   // (H,H)
    const float* bih = (const float*)d_in[3];   // (H)
    const float* bhh = (const float*)d_in[4];   // (H)
    float* out = (float*)d_out;                 // (B,S,H)

    unsigned int* cnt = (unsigned int*)d_ws;                        // 4 counters, 128-B spaced
    unsigned short* hbuf = (unsigned short*)((char*)d_ws + 1024);   // 2 x 64 x 1024 bf16

    hipMemsetAsync(d_ws, 0, 1024, stream);      // zero barrier counters every call

    dim3 gA(256, 8);
    xproj_gemm<<<gA, 256, 0, stream>>>(x, Wih, bih, bhh, out);
    rnn_steps<<<256, 256, 0, stream>>>(Whh, out, hbuf, cnt);
}